// Round 1
// baseline (1192.029 us; speedup 1.0000x reference)
//
#include <hip/hip_runtime.h>
#include <math.h>

#define Bb 64
#define Nn 1000
#define Gg 500
#define Hh 256
#define GP 512

// workspace layout (float offsets)
#define WS_MP 0                       // [B][4][H] mean partials
#define WS_QG (WS_MP + Bb*4*Hh)       // [B][H] q_graph
#define WS_RS (WS_QG + Bb*Hh)         // [B][G] row sums (padded region B*GP)
#define WS_PQ (WS_RS + Bb*GP)         // [B][GP][H] pooled -> final_q (in place)

__device__ __forceinline__ float tanh10(float s) {
  float a = fabsf(s);
  float e = __expf(-2.0f * a);
  float t = (1.0f - e) / (1.0f + e);
  return copysignf(10.0f * t, s);
}

// ---------------- mean partials: grid(B*4), block(256) ----------------
__global__ __launch_bounds__(256) void k_meanpart(const float* __restrict__ emb,
                                                  float* __restrict__ mp) {
  int b = blockIdx.x >> 2, part = blockIdx.x & 3;
  int h = threadIdx.x;
  const float* p = emb + ((size_t)b * Nn + part * 250) * Hh + h;
  float s = 0.f;
  for (int n = 0; n < 250; ++n) s += p[(size_t)n * Hh];
  mp[(b * 4 + part) * Hh + h] = s;
}

// ---------------- q_graph: grid(B), block(256) ----------------
__global__ __launch_bounds__(256) void k_qgraph(const float* __restrict__ mp,
                                                const float* __restrict__ Wg,
                                                float* __restrict__ qg) {
  __shared__ float mean[Hh];
  int b = blockIdx.x, t = threadIdx.x;
  mean[t] = (mp[(b*4+0)*Hh+t] + mp[(b*4+1)*Hh+t] + mp[(b*4+2)*Hh+t] + mp[(b*4+3)*Hh+t]) * (1.0f/Nn);
  __syncthreads();
  const float4* wrow = (const float4*)(Wg + (size_t)t * Hh);
  float acc = 0.f;
#pragma unroll
  for (int h4 = 0; h4 < Hh/4; ++h4) {
    float4 w = wrow[h4];
    acc += mean[h4*4]*w.x + mean[h4*4+1]*w.y + mean[h4*4+2]*w.z + mean[h4*4+3]*w.w;
  }
  qg[b*Hh + t] = acc;
}

// ---------------- pooled GEMM: grid(B*8), block(256) ----------------
// pooled[b,g,h] = (1/N) * sum_n visited[b,g,n] * emb[b,n,h]
__global__ __launch_bounds__(256) void k_pool(const float* __restrict__ emb,
                                              const float* __restrict__ gm,
                                              float* __restrict__ pq) {
  __shared__ float lA[16][64];
  __shared__ float lB[16][256];
  int b = blockIdx.x >> 3, g0 = (blockIdx.x & 7) << 6;
  int tid = threadIdx.x, ty = tid >> 5, tx = tid & 31;
  float acc[8][8];
#pragma unroll
  for (int i = 0; i < 8; i++)
#pragma unroll
    for (int j = 0; j < 8; j++) acc[i][j] = 0.f;

  int ar = tid >> 2, ac0 = (tid & 3) << 2;
  int br = tid >> 4, bc0 = (tid & 15) << 4;
  bool a_ok = (g0 + ar) < Gg;
  const size_t gm_row = ((size_t)b * Gg + (g0 + ar)) * Nn;

  for (int k0 = 0; k0 < 1008; k0 += 16) {
#pragma unroll
    for (int cc = 0; cc < 4; ++cc) {
      int n = k0 + ac0 + cc;
      float v = 0.f;
      if (a_ok && n < Nn) v = (gm[gm_row + n] < -1e30f) ? 1.0f : 0.0f;
      lA[ac0 + cc][ar] = v;
    }
    {
      int n = k0 + br;
      float4* d4 = (float4*)&lB[br][bc0];
      if (n < Nn) {
        const float4* s4 = (const float4*)(emb + ((size_t)b * Nn + n) * Hh + bc0);
        d4[0] = s4[0]; d4[1] = s4[1]; d4[2] = s4[2]; d4[3] = s4[3];
      } else {
        float4 z = {0.f, 0.f, 0.f, 0.f};
        d4[0] = z; d4[1] = z; d4[2] = z; d4[3] = z;
      }
    }
    __syncthreads();
#pragma unroll
    for (int k = 0; k < 16; ++k) {
      float4 a0 = *(const float4*)&lA[k][ty * 8];
      float4 a1 = *(const float4*)&lA[k][ty * 8 + 4];
      float4 b0 = *(const float4*)&lB[k][tx * 4];
      float4 b1 = *(const float4*)&lB[k][128 + tx * 4];
      float av[8] = {a0.x, a0.y, a0.z, a0.w, a1.x, a1.y, a1.z, a1.w};
      float bv[8] = {b0.x, b0.y, b0.z, b0.w, b1.x, b1.y, b1.z, b1.w};
#pragma unroll
      for (int i = 0; i < 8; i++)
#pragma unroll
        for (int j = 0; j < 8; j++) acc[i][j] = fmaf(av[i], bv[j], acc[i][j]);
    }
    __syncthreads();
  }
#pragma unroll
  for (int i = 0; i < 8; i++) {
    int g = g0 + ty * 8 + i;  // rows >= Gg hold zeros (A staged 0) -> clean pad
    float* row = pq + ((size_t)b * GP + g) * Hh;
    float4 v0 = {acc[i][0] * (1.f/Nn), acc[i][1] * (1.f/Nn), acc[i][2] * (1.f/Nn), acc[i][3] * (1.f/Nn)};
    float4 v1 = {acc[i][4] * (1.f/Nn), acc[i][5] * (1.f/Nn), acc[i][6] * (1.f/Nn), acc[i][7] * (1.f/Nn)};
    *(float4*)&row[tx * 4] = v0;
    *(float4*)&row[128 + tx * 4] = v1;
  }
}

// ---------------- final_q: grid(B*8), block(256) ----------------
// final_q[b,g,o] = sum_h pooled[g,h]*Wv[o,h] + sum_h emb[b,L[g],h]*(Wl+Wf)[o,h] + qg[b,o]
// written in place over pq.
__global__ __launch_bounds__(256) void k_finalq(const float* __restrict__ emb,
                                                const int* __restrict__ last_node,
                                                const float* __restrict__ Wf,
                                                const float* __restrict__ Wl,
                                                const float* __restrict__ Wv,
                                                const float* __restrict__ qg,
                                                float* __restrict__ pq) {
  __shared__ float lA[16][64];
  __shared__ float lB[16][256];
  __shared__ int lL[64];
  __shared__ float lQ[256];
  int b = blockIdx.x >> 3, g0 = (blockIdx.x & 7) << 6;
  int tid = threadIdx.x, ty = tid >> 5, tx = tid & 31;
  if (tid < 64) {
    int g = g0 + tid;
    lL[tid] = (g < Gg) ? last_node[b * Gg + g] : 0;
  }
  lQ[tid] = qg[b * Hh + tid];
  __syncthreads();

  float acc[8][8];
#pragma unroll
  for (int i = 0; i < 8; i++)
#pragma unroll
    for (int j = 0; j < 8; j++) acc[i][j] = 0.f;

  int ar = tid >> 2, ac0 = (tid & 3) << 2;
  int br = tid >> 4, bc0 = (tid & 15) << 4;

  for (int k0 = 0; k0 < 512; k0 += 16) {
#pragma unroll
    for (int cc = 0; cc < 4; ++cc) {
      int k = k0 + ac0 + cc;
      float v;
      if (k < 256) v = pq[((size_t)b * GP + g0 + ar) * Hh + k];
      else         v = emb[((size_t)b * Nn + lL[ar]) * Hh + (k - 256)];
      lA[ac0 + cc][ar] = v;
    }
    {
      int k = k0 + br;
#pragma unroll
      for (int oo = 0; oo < 16; ++oo) {
        int o = bc0 + oo;
        float v;
        if (k < 256) v = Wv[o * Hh + k];
        else         v = Wl[o * Hh + (k - 256)] + Wf[o * Hh + (k - 256)];
        lB[br][o] = v;
      }
    }
    __syncthreads();
#pragma unroll
    for (int k = 0; k < 16; ++k) {
      float4 a0 = *(const float4*)&lA[k][ty * 8];
      float4 a1 = *(const float4*)&lA[k][ty * 8 + 4];
      float4 b0 = *(const float4*)&lB[k][tx * 4];
      float4 b1 = *(const float4*)&lB[k][128 + tx * 4];
      float av[8] = {a0.x, a0.y, a0.z, a0.w, a1.x, a1.y, a1.z, a1.w};
      float bv[8] = {b0.x, b0.y, b0.z, b0.w, b1.x, b1.y, b1.z, b1.w};
#pragma unroll
      for (int i = 0; i < 8; i++)
#pragma unroll
        for (int j = 0; j < 8; j++) acc[i][j] = fmaf(av[i], bv[j], acc[i][j]);
    }
    __syncthreads();
  }
#pragma unroll
  for (int i = 0; i < 8; i++) {
    int g = g0 + ty * 8 + i;
    float* row = pq + ((size_t)b * GP + g) * Hh;
    float4 v0 = {acc[i][0] + lQ[tx*4+0], acc[i][1] + lQ[tx*4+1],
                 acc[i][2] + lQ[tx*4+2], acc[i][3] + lQ[tx*4+3]};
    float4 v1 = {acc[i][4] + lQ[128+tx*4+0], acc[i][5] + lQ[128+tx*4+1],
                 acc[i][6] + lQ[128+tx*4+2], acc[i][7] + lQ[128+tx*4+3]};
    *(float4*)&row[tx * 4] = v0;
    *(float4*)&row[128 + tx * 4] = v1;
  }
}

// ---------------- score + masked exp + row sums: grid(B*8), block(256) ----------------
__global__ __launch_bounds__(256) void k_score(const float* __restrict__ emb,
                                               const float* __restrict__ dists,
                                               const int* __restrict__ last_node,
                                               const float* __restrict__ gm,
                                               const float* __restrict__ fq,
                                               float* __restrict__ out,
                                               float* __restrict__ rs) {
  __shared__ float lA[16][64];
  __shared__ float lB[16][256];
  __shared__ int lL[64];
  __shared__ float lR[64][32];
  int b = blockIdx.x >> 3, g0 = (blockIdx.x & 7) << 6;
  int tid = threadIdx.x, ty = tid >> 5, tx = tid & 31;
  if (tid < 64) {
    int g = g0 + tid;
    lL[tid] = (g < Gg) ? last_node[b * Gg + g] : 0;
  }
  __syncthreads();
  float rsum[8];
#pragma unroll
  for (int i = 0; i < 8; i++) rsum[i] = 0.f;
  int ar = tid >> 2, ac0 = (tid & 3) << 2;

  for (int t = 0; t < 4; ++t) {
    int n0 = t << 8;
    float acc[8][8];
#pragma unroll
    for (int i = 0; i < 8; i++)
#pragma unroll
      for (int j = 0; j < 8; j++) acc[i][j] = 0.f;

    for (int k0 = 0; k0 < 256; k0 += 16) {
#pragma unroll
      for (int cc = 0; cc < 4; ++cc) {
        int k = k0 + ac0 + cc;
        lA[ac0 + cc][ar] = fq[((size_t)b * GP + g0 + ar) * Hh + k];
      }
      {
        int n = n0 + tid;
        if (n < Nn) {
          const float4* s4 = (const float4*)(emb + ((size_t)b * Nn + n) * Hh + k0);
#pragma unroll
          for (int q = 0; q < 4; ++q) {
            float4 v = s4[q];
            lB[q*4+0][tid] = v.x; lB[q*4+1][tid] = v.y;
            lB[q*4+2][tid] = v.z; lB[q*4+3][tid] = v.w;
          }
        } else {
#pragma unroll
          for (int c = 0; c < 16; ++c) lB[c][tid] = 0.f;
        }
      }
      __syncthreads();
#pragma unroll
      for (int k = 0; k < 16; ++k) {
        float4 a0 = *(const float4*)&lA[k][ty * 8];
        float4 a1 = *(const float4*)&lA[k][ty * 8 + 4];
        float4 b0 = *(const float4*)&lB[k][tx * 4];
        float4 b1 = *(const float4*)&lB[k][128 + tx * 4];
        float av[8] = {a0.x, a0.y, a0.z, a0.w, a1.x, a1.y, a1.z, a1.w};
        float bv[8] = {b0.x, b0.y, b0.z, b0.w, b1.x, b1.y, b1.z, b1.w};
#pragma unroll
        for (int i = 0; i < 8; i++)
#pragma unroll
          for (int j = 0; j < 8; j++) acc[i][j] = fmaf(av[i], bv[j], acc[i][j]);
      }
      __syncthreads();
    }
    // epilogue: score -> 10*tanh -> mask -> exp(c-10), write unnormalized
#pragma unroll
    for (int i = 0; i < 8; i++) {
      int gl = ty * 8 + i, g = g0 + gl;
      if (g < Gg) {
        const size_t orow = ((size_t)b * Gg + g) * Nn;
        const size_t drow = ((size_t)b * Nn + lL[gl]) * Nn;
#pragma unroll
        for (int j = 0; j < 8; j++) {
          int c = (j < 4) ? (tx * 4 + j) : (128 + tx * 4 + (j - 4));
          int n = n0 + c;
          if (n < Nn) {
            float s = acc[i][j] * 0.0625f - dists[drow + n] * 0.70710678118f;
            float m = gm[orow + n];
            float p = (m < -1e30f) ? 0.f : __expf(tanh10(s) - 10.0f);
            out[orow + n] = p;
            rsum[i] += p;
          }
        }
      }
    }
  }
#pragma unroll
  for (int i = 0; i < 8; i++) lR[ty * 8 + i][tx] = rsum[i];
  __syncthreads();
  if (tid < 64) {
    float s = 0.f;
#pragma unroll
    for (int x = 0; x < 32; x++) s += lR[tid][x];
    int g = g0 + tid;
    if (g < Gg) rs[b * Gg + g] = s;
  }
}

// ---------------- normalize: out /= rowsum ----------------
__global__ __launch_bounds__(256) void k_norm(float* __restrict__ out,
                                              const float* __restrict__ rs) {
  int idx = blockIdx.x * 256 + threadIdx.x;  // float4 index
  if (idx >= Bb * Gg * Nn / 4) return;
  int bg = idx / 250;                        // = b*Gg + g
  float inv = 1.0f / rs[bg];
  float4* p = (float4*)out + idx;
  float4 v = *p;
  v.x *= inv; v.y *= inv; v.z *= inv; v.w *= inv;
  *p = v;
}

extern "C" void kernel_launch(void* const* d_in, const int* in_sizes, int n_in,
                              void* d_out, int out_size, void* d_ws, size_t ws_size,
                              hipStream_t stream) {
  const float* emb       = (const float*)d_in[0];
  const float* dists     = (const float*)d_in[1];
  const int*   last_node = (const int*)d_in[2];
  const float* gm        = (const float*)d_in[3];
  const float* Wg        = (const float*)d_in[4];
  const float* Wf        = (const float*)d_in[5];
  const float* Wl        = (const float*)d_in[6];
  const float* Wv        = (const float*)d_in[7];
  float* out = (float*)d_out;
  float* ws  = (float*)d_ws;
  float* mp = ws + WS_MP;
  float* qg = ws + WS_QG;
  float* rs = ws + WS_RS;
  float* pq = ws + WS_PQ;

  hipLaunchKernelGGL(k_meanpart, dim3(Bb * 4), dim3(256), 0, stream, emb, mp);
  hipLaunchKernelGGL(k_qgraph,   dim3(Bb),     dim3(256), 0, stream, mp, Wg, qg);
  hipLaunchKernelGGL(k_pool,     dim3(Bb * 8), dim3(256), 0, stream, emb, gm, pq);
  hipLaunchKernelGGL(k_finalq,   dim3(Bb * 8), dim3(256), 0, stream, emb, last_node, Wf, Wl, Wv, qg, pq);
  hipLaunchKernelGGL(k_score,    dim3(Bb * 8), dim3(256), 0, stream, emb, dists, last_node, gm, pq, out, rs);
  hipLaunchKernelGGL(k_norm,     dim3((Bb * Gg * Nn / 4 + 255) / 256), dim3(256), 0, stream, out, rs);
}

// Round 2
// 632.837 us; speedup vs baseline: 1.8836x; 1.8836x over previous
//
#include <hip/hip_runtime.h>
#include <math.h>

#define Bb 64
#define Nn 1000
#define Gg 500
#define Hh 256
#define GP 512

// workspace layout (float offsets)
#define WS_MP 0u                      // [B][4][H] mean partials
#define WS_QG 65536u                  // [B][H] q_graph
#define WS_RS 81920u                  // [B][GP] row sums
#define WS_WC 114688u                 // [256][512] Wcat (o-major, k-contiguous)
#define WS_PL 245760u                 // [B][GP][H] pooled
#define WS_LE 8634368u                // [B][GP][H] gathered last-node emb
#define WS_FQ 17022976u               // [B][GP][H] final_q

typedef __attribute__((ext_vector_type(8))) short bf16x8;
typedef __attribute__((ext_vector_type(4))) float f32x4;

#define MFMA(a, b, c) __builtin_amdgcn_mfma_f32_16x16x32_bf16(a, b, c, 0, 0, 0)

__device__ __forceinline__ float tanh10(float s) {
  float a = fabsf(s);
  float e = __expf(-2.0f * a);
  float t = (1.0f - e) / (1.0f + e);
  return copysignf(10.0f * t, s);
}

__device__ __forceinline__ void load8(const float* __restrict__ p, float x[8]) {
  float4 a = ((const float4*)p)[0];
  float4 b = ((const float4*)p)[1];
  x[0]=a.x; x[1]=a.y; x[2]=a.z; x[3]=a.w; x[4]=b.x; x[5]=b.y; x[6]=b.z; x[7]=b.w;
}

// Dekker-style split: hi = trunc16(x) (exact residual), lo = trunc16(x - hi)
__device__ __forceinline__ void cvt_split(const float x[8], bf16x8& hi, bf16x8& lo) {
#pragma unroll
  for (int i = 0; i < 8; ++i) {
    unsigned bits = __float_as_uint(x[i]);
    hi[i] = (short)(bits >> 16);
    float hf = __uint_as_float(bits & 0xFFFF0000u);
    float l = x[i] - hf;
    lo[i] = (short)(__float_as_uint(l) >> 16);
  }
}

// ---------------- mean partials: grid(B*4), block(256) ----------------
__global__ __launch_bounds__(256) void k_meanpart(const float* __restrict__ emb,
                                                  float* __restrict__ mp) {
  int b = blockIdx.x >> 2, part = blockIdx.x & 3;
  int h = threadIdx.x;
  const float* p = emb + ((size_t)b * Nn + part * 250) * Hh + h;
  float s = 0.f;
  for (int n = 0; n < 250; ++n) s += p[(size_t)n * Hh];
  mp[(b * 4 + part) * Hh + h] = s;
}

// ---------------- q_graph: grid(B), block(256) ----------------
__global__ __launch_bounds__(256) void k_qgraph(const float* __restrict__ mp,
                                                const float* __restrict__ Wg,
                                                float* __restrict__ qg) {
  __shared__ float mean[Hh];
  int b = blockIdx.x, t = threadIdx.x;
  mean[t] = (mp[(b*4+0)*Hh+t] + mp[(b*4+1)*Hh+t] + mp[(b*4+2)*Hh+t] + mp[(b*4+3)*Hh+t]) * (1.0f/Nn);
  __syncthreads();
  const float4* wrow = (const float4*)(Wg + (size_t)t * Hh);
  float acc = 0.f;
#pragma unroll
  for (int h4 = 0; h4 < Hh/4; ++h4) {
    float4 w = wrow[h4];
    acc += mean[h4*4]*w.x + mean[h4*4+1]*w.y + mean[h4*4+2]*w.z + mean[h4*4+3]*w.w;
  }
  qg[b*Hh + t] = acc;
}

// ---------------- Wcat[o][k] = k<256 ? Wv[o][k] : Wl+Wf : grid(256), block(256) ----
__global__ __launch_bounds__(256) void k_wcat(const float* __restrict__ Wf,
                                              const float* __restrict__ Wl,
                                              const float* __restrict__ Wv,
                                              float* __restrict__ Wcat) {
  int o = blockIdx.x, k = threadIdx.x;
  Wcat[o*512 + k]       = Wv[o*256 + k];
  Wcat[o*512 + 256 + k] = Wl[o*256 + k] + Wf[o*256 + k];
}

// ---------------- gather last-node rows: grid(B*512), block(64) ----------------
__global__ __launch_bounds__(64) void k_gather(const float* __restrict__ emb,
                                               const int* __restrict__ last_node,
                                               float* __restrict__ lastE) {
  int bg = blockIdx.x, b = bg >> 9, g = bg & 511;
  int L = last_node[b * Gg + (g < Gg ? g : Gg - 1)];
  const float4* src = (const float4*)(emb + ((size_t)b * Nn + L) * Hh);
  float4* dst = (float4*)(lastE + ((size_t)b * GP + g) * Hh);
  dst[threadIdx.x] = src[threadIdx.x];
}

// ---------------- zero row sums: grid(128), block(256) ----------------
__global__ __launch_bounds__(256) void k_zero(float* __restrict__ rs) {
  rs[blockIdx.x * 256 + threadIdx.x] = 0.f;
}

// ---------------- pool MFMA: C[b][g][h] = (1/N) mask @ emb ----------------
// grid(ht=2, gt=8, b=64), block(256)=4 waves (2x2), wave tile 32x64
__global__ __launch_bounds__(256) void k_pool(const float* __restrict__ emb,
                                              const float* __restrict__ gm,
                                              float* __restrict__ pooled) {
  int ht = blockIdx.x, gt = blockIdx.y, b = blockIdx.z;
  int tid = threadIdx.x, w = tid >> 6, lane = tid & 63;
  int wr = w >> 1, wc = w & 1, l15 = lane & 15, lk = lane >> 4;
  f32x4 acc[2][4] = {};

  int grow[2];
  grow[0] = gt*64 + wr*32 + l15;
  grow[1] = grow[0] + 16;
  int hcol0 = ht*128 + wc*64;

  for (int k0 = 0; k0 < 992; k0 += 32) {
    bf16x8 am[2], bhi[4], blo[4];
#pragma unroll
    for (int fm = 0; fm < 2; ++fm) {
      float x[8] = {0,0,0,0,0,0,0,0};
      if (grow[fm] < Gg) load8(gm + ((size_t)b*Gg + grow[fm])*Nn + k0 + lk*8, x);
#pragma unroll
      for (int i = 0; i < 8; ++i) am[fm][i] = (x[i] < -1e30f) ? (short)0x3F80 : (short)0;
    }
#pragma unroll
    for (int fn = 0; fn < 4; ++fn) {
      int h = hcol0 + fn*16 + l15;
      float x[8];
#pragma unroll
      for (int i = 0; i < 8; ++i) {
        int n = k0 + lk*8 + i;
        x[i] = emb[((size_t)b*Nn + n)*Hh + h];
      }
      cvt_split(x, bhi[fn], blo[fn]);
    }
#pragma unroll
    for (int fm = 0; fm < 2; ++fm)
#pragma unroll
      for (int fn = 0; fn < 4; ++fn) {
        acc[fm][fn] = MFMA(am[fm], bhi[fn], acc[fm][fn]);
        acc[fm][fn] = MFMA(am[fm], blo[fn], acc[fm][fn]);
      }
  }
  { // tail k0 = 992, valid n < 1000
    const int k0 = 992;
    bf16x8 am[2], bhi[4], blo[4];
#pragma unroll
    for (int fm = 0; fm < 2; ++fm) {
#pragma unroll
      for (int i = 0; i < 8; ++i) {
        int n = k0 + lk*8 + i;
        float v = 0.f;
        if (grow[fm] < Gg && n < Nn) v = gm[((size_t)b*Gg + grow[fm])*Nn + n];
        am[fm][i] = (v < -1e30f) ? (short)0x3F80 : (short)0;
      }
    }
#pragma unroll
    for (int fn = 0; fn < 4; ++fn) {
      int h = hcol0 + fn*16 + l15;
      float x[8];
#pragma unroll
      for (int i = 0; i < 8; ++i) {
        int n = k0 + lk*8 + i; if (n > Nn-1) n = Nn-1;
        x[i] = emb[((size_t)b*Nn + n)*Hh + h];
      }
      cvt_split(x, bhi[fn], blo[fn]);
    }
#pragma unroll
    for (int fm = 0; fm < 2; ++fm)
#pragma unroll
      for (int fn = 0; fn < 4; ++fn) {
        acc[fm][fn] = MFMA(am[fm], bhi[fn], acc[fm][fn]);
        acc[fm][fn] = MFMA(am[fm], blo[fn], acc[fm][fn]);
      }
  }
  // epilogue: store fp32 (pad rows g>=500 are exact zeros)
#pragma unroll
  for (int fm = 0; fm < 2; ++fm)
#pragma unroll
    for (int j = 0; j < 4; ++j) {
      int g = gt*64 + wr*32 + fm*16 + lk*4 + j;
#pragma unroll
      for (int fn = 0; fn < 4; ++fn) {
        int h = hcol0 + fn*16 + l15;
        pooled[((size_t)b*GP + g)*Hh + h] = acc[fm][fn][j] * (1.0f/Nn);
      }
    }
}

// ---------------- finalq MFMA: fq = [pooled|lastE] @ Wcat^T + qg ----------------
// grid(ot=2, gt=8, b=64), block(256)
__global__ __launch_bounds__(256) void k_finalq(const float* __restrict__ pooled,
                                                const float* __restrict__ lastE,
                                                const float* __restrict__ Wcat,
                                                const float* __restrict__ qg,
                                                float* __restrict__ fq) {
  int ot = blockIdx.x, gt = blockIdx.y, b = blockIdx.z;
  int tid = threadIdx.x, w = tid >> 6, lane = tid & 63;
  int wr = w >> 1, wc = w & 1, l15 = lane & 15, lk = lane >> 4;
  f32x4 acc[2][4] = {};
  int ocol0 = ot*128 + wc*64;

  for (int k0 = 0; k0 < 512; k0 += 32) {
    const float* Asrc = (k0 < 256) ? pooled : lastE;
    int kk = k0 & 255;
    bf16x8 ahi[2], alo[2], bhi[4], blo[4];
#pragma unroll
    for (int fm = 0; fm < 2; ++fm) {
      float x[8];
      load8(Asrc + ((size_t)b*GP + gt*64 + wr*32 + fm*16 + l15)*Hh + kk + lk*8, x);
      cvt_split(x, ahi[fm], alo[fm]);
    }
#pragma unroll
    for (int fn = 0; fn < 4; ++fn) {
      float x[8];
      load8(Wcat + (ocol0 + fn*16 + l15)*512 + k0 + lk*8, x);
      cvt_split(x, bhi[fn], blo[fn]);
    }
#pragma unroll
    for (int fm = 0; fm < 2; ++fm)
#pragma unroll
      for (int fn = 0; fn < 4; ++fn) {
        acc[fm][fn] = MFMA(ahi[fm], bhi[fn], acc[fm][fn]);
        acc[fm][fn] = MFMA(ahi[fm], blo[fn], acc[fm][fn]);
        acc[fm][fn] = MFMA(alo[fm], bhi[fn], acc[fm][fn]);
      }
  }
  float qv[4];
#pragma unroll
  for (int fn = 0; fn < 4; ++fn) qv[fn] = qg[b*Hh + ocol0 + fn*16 + l15];
#pragma unroll
  for (int fm = 0; fm < 2; ++fm)
#pragma unroll
    for (int j = 0; j < 4; ++j) {
      int g = gt*64 + wr*32 + fm*16 + lk*4 + j;
#pragma unroll
      for (int fn = 0; fn < 4; ++fn) {
        int o = ocol0 + fn*16 + l15;
        fq[((size_t)b*GP + g)*Hh + o] = acc[fm][fn][j] + qv[fn];
      }
    }
}

// ---------------- score MFMA + softmax-num + rowsum atomics ----------------
// grid(nt=8, gt=8, b=64), block(256)
__global__ __launch_bounds__(256) void k_score(const float* __restrict__ emb,
                                               const float* __restrict__ dists,
                                               const int* __restrict__ last_node,
                                               const float* __restrict__ gm,
                                               const float* __restrict__ fq,
                                               float* __restrict__ out,
                                               float* __restrict__ rs) {
  int nt = blockIdx.x, gt = blockIdx.y, b = blockIdx.z;
  int tid = threadIdx.x, w = tid >> 6, lane = tid & 63;
  int wr = w >> 1, wc = w & 1, l15 = lane & 15, lk = lane >> 4;
  __shared__ int lL[64];
  if (tid < 64) {
    int g = gt*64 + tid;
    lL[tid] = last_node[b*Gg + (g < Gg ? g : Gg-1)];
  }
  __syncthreads();

  f32x4 acc[2][4] = {};
  const float* Abase = fq + ((size_t)b*GP + gt*64 + wr*32)*Hh;
  int ncol0 = nt*128 + wc*64;

  for (int k0 = 0; k0 < 256; k0 += 32) {
    bf16x8 ahi[2], alo[2], bhi[4], blo[4];
#pragma unroll
    for (int fm = 0; fm < 2; ++fm) {
      float x[8];
      load8(Abase + (fm*16 + l15)*Hh + k0 + lk*8, x);
      cvt_split(x, ahi[fm], alo[fm]);
    }
#pragma unroll
    for (int fn = 0; fn < 4; ++fn) {
      int n = ncol0 + fn*16 + l15; if (n > Nn-1) n = Nn-1;
      float x[8];
      load8(emb + ((size_t)b*Nn + n)*Hh + k0 + lk*8, x);
      cvt_split(x, bhi[fn], blo[fn]);
    }
#pragma unroll
    for (int fm = 0; fm < 2; ++fm)
#pragma unroll
      for (int fn = 0; fn < 4; ++fn) {
        acc[fm][fn] = MFMA(ahi[fm], bhi[fn], acc[fm][fn]);
        acc[fm][fn] = MFMA(ahi[fm], blo[fn], acc[fm][fn]);
        acc[fm][fn] = MFMA(alo[fm], bhi[fn], acc[fm][fn]);
      }
  }
  // epilogue
#pragma unroll
  for (int fm = 0; fm < 2; ++fm) {
#pragma unroll
    for (int j = 0; j < 4; ++j) {
      int grow = gt*64 + wr*32 + fm*16 + lk*4 + j;
      float s = 0.f;
      if (grow < Gg) {
        int L = lL[wr*32 + fm*16 + lk*4 + j];
        size_t drow = ((size_t)b*Nn + L)*Nn;
        size_t orow = ((size_t)b*Gg + grow)*Nn;
#pragma unroll
        for (int fn = 0; fn < 4; ++fn) {
          int n = ncol0 + fn*16 + l15;
          float p = 0.f;
          if (n < Nn) {
            float sc = acc[fm][fn][j] * 0.0625f - dists[drow + n] * 0.70710678118654752f;
            p = (gm[orow + n] < -1e30f) ? 0.f : __expf(tanh10(sc) - 10.0f);
            out[orow + n] = p;
          }
          s += p;
        }
      }
      s += __shfl_xor(s, 1); s += __shfl_xor(s, 2);
      s += __shfl_xor(s, 4); s += __shfl_xor(s, 8);
      if (grow < Gg && l15 == 0) atomicAdd(&rs[b*GP + grow], s);
    }
  }
}

// ---------------- normalize: out /= rowsum ----------------
__global__ __launch_bounds__(256) void k_norm(float* __restrict__ out,
                                              const float* __restrict__ rs) {
  int idx = blockIdx.x * 256 + threadIdx.x;  // float4 index
  int bg = idx / 250;                        // = b*Gg + g
  int b = bg / Gg, g = bg - b * Gg;
  float inv = 1.0f / rs[b*GP + g];
  float4* p = (float4*)out + idx;
  float4 v = *p;
  v.x *= inv; v.y *= inv; v.z *= inv; v.w *= inv;
  *p = v;
}

extern "C" void kernel_launch(void* const* d_in, const int* in_sizes, int n_in,
                              void* d_out, int out_size, void* d_ws, size_t ws_size,
                              hipStream_t stream) {
  const float* emb       = (const float*)d_in[0];
  const float* dists     = (const float*)d_in[1];
  const int*   last_node = (const int*)d_in[2];
  const float* gm        = (const float*)d_in[3];
  const float* Wg        = (const float*)d_in[4];
  const float* Wf        = (const float*)d_in[5];
  const float* Wl        = (const float*)d_in[6];
  const float* Wv        = (const float*)d_in[7];
  float* out = (float*)d_out;
  float* ws  = (float*)d_ws;
  float* mp    = ws + WS_MP;
  float* qg    = ws + WS_QG;
  float* rs    = ws + WS_RS;
  float* Wcat  = ws + WS_WC;
  float* pooled= ws + WS_PL;
  float* lastE = ws + WS_LE;
  float* fq    = ws + WS_FQ;

  hipLaunchKernelGGL(k_meanpart, dim3(Bb*4), dim3(256), 0, stream, emb, mp);
  hipLaunchKernelGGL(k_qgraph,   dim3(Bb),   dim3(256), 0, stream, mp, Wg, qg);
  hipLaunchKernelGGL(k_wcat,     dim3(256),  dim3(256), 0, stream, Wf, Wl, Wv, Wcat);
  hipLaunchKernelGGL(k_gather,   dim3(Bb*GP),dim3(64),  0, stream, emb, last_node, lastE);
  hipLaunchKernelGGL(k_zero,     dim3(Bb*GP/256), dim3(256), 0, stream, rs);
  hipLaunchKernelGGL(k_pool,     dim3(2,8,Bb), dim3(256), 0, stream, emb, gm, pooled);
  hipLaunchKernelGGL(k_finalq,   dim3(2,8,Bb), dim3(256), 0, stream, pooled, lastE, Wcat, qg, fq);
  hipLaunchKernelGGL(k_score,    dim3(8,8,Bb), dim3(256), 0, stream, emb, dists, last_node, gm, fq, out, rs);
  hipLaunchKernelGGL(k_norm,     dim3(Bb*Gg*Nn/4/256), dim3(256), 0, stream, out, rs);
}